// Round 8
// baseline (783.186 us; speedup 1.0000x reference)
//
#include <hip/hip_runtime.h>

// AdjointODE: h += dt * ( tanh(h@W1+b1) @ W2 + b2 ), 50 Euler steps.
// BATCH=32768, DIM=128, HID=256.
// ROUND 17: AGPR W2 CACHE WITH COMPILER-MANAGED HAZARD BOUNDARIES.
// r16 post-mortem: NaN. Math was order-identical to r14 (passed), so the
// corruption is mechanical: inline-asm MFMA bypasses LLVM's hazard-nop
// insertion. Missing waits: (a) VALU cvt_pk write of af -> asm-MFMA SrcB
// read (needs ~2 wait states); (b) asm-MFMA D write -> VALU read of h4
// (b2-add / next-step packfrag). Fixes:
//  1. "s_nop 1" PREFIX inside mfma_a (covers VALU->MFMA SrcA/B at every
//     asm use; ~2cyc x 96 = noise under the 16cyc/SIMD MFMA shadow);
//  2. SANDWICH: W2 chunks 0 AND 7 stream from LDS and use the BUILTIN
//     MFMA (compiler inserts trailing hazard nops before VALU reads of
//     h4). Asm-MFMAs (chunks 1..6) only feed other MFMAs as SrcC --
//     hardware-legal back-to-back chaining, no nops needed.
//  3. AGPR cache = chunks 1..6 = 48 frags = 192 AGPRs (was 256: also
//     removes the at-the-ceiling allocation risk). w2r0 dead after p=1,
//     w2r7 loaded in p==7's window -> peak arch ~250 < 256.
// LDS/wave-step: W1 64 + W2 16 + b1/b2 ~24 = ~104 b128 -> 416/CU ~= 5k
// cyc floor (~104us) vs MFMA 2k.
// Canary: FETCH ~9.3MB / WRITE 16MB; NaN => abandon asm route, revert
// r11 (278us) final; GB-FETCH => same.
// Else = r16: 32 rows/wave (two 16-row B-groups), (256,1), W1 dbuf,
// bi prefetch, fragment-linear LDS, h fp32-resident, pk2, b2 from LDS.

typedef __attribute__((ext_vector_type(8))) short short8;
typedef __attribute__((ext_vector_type(4))) float float4v;
typedef __attribute__((ext_vector_type(4))) int int4v;

union FB { int4v i; short8 s; };

// LDS map (bytes)
#define W1F_OFF 0        // 64 frags (nt*4+c) x 1 KB = 64 KB
#define W2F_OFF 65536    // 64 frags (p*8+tb) x 1 KB = 64 KB
#define B1_OFF  131072   // f32[256] (TSCALE-folded b1)
#define DT_OFF  132096   // f32[64]
#define B2_OFF  132352   // f32[128]
#define LDS_BYTES 132864

#define TSCALE 2.8853900817779268f  // 2/ln2: tanh(x) = 1 - 2/(exp2(x*TSCALE)+1)

__device__ __forceinline__ unsigned rne2(float x) {
  unsigned u = __float_as_uint(x);
  return u + 0x7fffu + ((u >> 16) & 1u);
}

#if __has_builtin(__builtin_amdgcn_cvt_pk_bf16_f32)
__device__ __forceinline__ int pk2(float lo, float hi) {
  return __builtin_bit_cast(int, __builtin_amdgcn_cvt_pk_bf16_f32(lo, hi));
}
#else
__device__ __forceinline__ int pk2(float lo, float hi) {
  return (int)__builtin_amdgcn_perm(rne2(hi), rne2(lo), 0x07060302u);
}
#endif

// B-frag for one 32-K chunk from two C-layout float4 tiles (even, odd).
__device__ __forceinline__ int4v packfrag(float4v e, float4v o) {
  int4v f;
  f.x = pk2(e.x, e.y);
  f.y = pk2(e.z, e.w);
  f.z = pk2(o.x, o.y);
  f.w = pk2(o.z, o.w);
  return f;
}

#define MFMA16(a, b, c) __builtin_amdgcn_mfma_f32_16x16x32_bf16(a, b, c, 0, 0, 0)

// mm2 MFMA with A operand pinned to AGPR class at every use.
// s_nop 1 prefix = 2 wait states for any preceding VALU write of an
// operand (the hazard the compiler can't see inside the asm).
__device__ __forceinline__ void mfma_a(float4v& acc, const short8& w, const short8& b) {
  asm("s_nop 1\n\tv_mfma_f32_16x16x32_bf16 %0, %1, %2, %0"
      : "+v"(acc) : "a"(w), "v"(b));
}

extern "C" __global__ __launch_bounds__(256, 1)
void ode_kernel(const float* __restrict__ inp, const float* __restrict__ ts,
                const float* __restrict__ W1, const float* __restrict__ b1,
                const float* __restrict__ W2, const float* __restrict__ b2,
                float* __restrict__ out) {
  __shared__ __align__(16) char ldsb[LDS_BYTES];
  float* b1f = (float*)(ldsb + B1_OFF);
  float* dtf = (float*)(ldsb + DT_OFF);
  float* b2f = (float*)(ldsb + B2_OFF);

  const int tid = threadIdx.x;
  const int lane = tid & 63, wave = tid >> 6;
  const int ln = lane & 15;  // batch-row within group
  const int q = lane >> 4;   // quad
  const int rowa = blockIdx.x * 128 + wave * 32 + ln;  // group A row
  const int rowb = rowa + 16;                          // group B row

  // ---- stage W1 frags: pi = (fid=nt*4+c)*64 + L; 256 thr x 16 iters ----
  #pragma unroll 1
  for (int it = 0; it < 16; it++) {
    const int pi = it * 256 + tid;  // [0, 4096)
    const int fid = pi >> 6, L = pi & 63;
    const int nt = fid >> 2, c = fid & 3;
    const int lf = L & 15, qf = L >> 4;
    const int n = nt * 16 + lf;            // hid index (A-frag m-row)
    const int kb = c * 32 + qf * 4;        // logical dim base
    float v0 = W1[(kb + 0) * 256 + n] * TSCALE;
    float v1 = W1[(kb + 1) * 256 + n] * TSCALE;
    float v2 = W1[(kb + 2) * 256 + n] * TSCALE;
    float v3 = W1[(kb + 3) * 256 + n] * TSCALE;
    float v4 = W1[(kb + 16) * 256 + n] * TSCALE;
    float v5 = W1[(kb + 17) * 256 + n] * TSCALE;
    float v6 = W1[(kb + 18) * 256 + n] * TSCALE;
    float v7 = W1[(kb + 19) * 256 + n] * TSCALE;
    int4v d = {pk2(v0, v1), pk2(v2, v3), pk2(v4, v5), pk2(v6, v7)};
    *(int4v*)(ldsb + W1F_OFF + pi * 16) = d;
  }
  // ---- stage W2 frags: fid = p*8 + tb ----
  #pragma unroll 1
  for (int it = 0; it < 16; it++) {
    const int pi = it * 256 + tid;
    const int fid = pi >> 6, L = pi & 63;
    const int p = fid >> 3, tb = fid & 7;
    const int lf = L & 15, qf = L >> 4;
    const int d_out = tb * 16 + lf;        // output-dim (A-frag m-row)
    const int kb = p * 32 + qf * 4;        // logical hid base
    float v0 = W2[(kb + 0) * 128 + d_out];
    float v1 = W2[(kb + 1) * 128 + d_out];
    float v2 = W2[(kb + 2) * 128 + d_out];
    float v3 = W2[(kb + 3) * 128 + d_out];
    float v4 = W2[(kb + 16) * 128 + d_out];
    float v5 = W2[(kb + 17) * 128 + d_out];
    float v6 = W2[(kb + 18) * 128 + d_out];
    float v7 = W2[(kb + 19) * 128 + d_out];
    int4v d = {pk2(v0, v1), pk2(v2, v3), pk2(v4, v5), pk2(v6, v7)};
    *(int4v*)(ldsb + W2F_OFF + pi * 16) = d;
  }
  b1f[tid] = b1[tid] * TSCALE;       // 256 threads == 256 entries
  if (tid < 128) b2f[tid] = b2[tid];
  if (tid < 50) dtf[tid] = ts[tid + 1] - ts[tid];

  // ---- load h for both groups ----
  float4v h4a[8], h4b[8];
  #pragma unroll
  for (int tb = 0; tb < 8; tb++) {
    h4a[tb] = *(const float4v*)&inp[rowa * 128 + tb * 16 + q * 4];
    h4b[tb] = *(const float4v*)&inp[rowb * 128 + tb * 16 + q * 4];
  }

  __syncthreads();  // the only barrier

  // per-lane frag base pointers
  const int4v* w1f = (const int4v*)(ldsb + W1F_OFF) + lane;
  const int4v* w2f = (const int4v*)(ldsb + W2F_OFF) + lane;

  // ---- W2 chunks 1..6 into AGPRs (class bound by mfma_a "a" uses) ----
  short8 w2c[48];
  #pragma unroll
  for (int i = 0; i < 48; i++)
    w2c[i] = __builtin_bit_cast(short8, w2f[(8 + i) * 64]);

  // ---- s-invariant b1 C-init for chunk 0 (hoisted) ----
  const float4v bc0_0 = *(const float4v*)&b1f[0 * 16 + q * 4];
  const float4v bc0_1 = *(const float4v*)&b1f[1 * 16 + q * 4];

  // ---- W1 double buffer; prologue: chunk 0 -> wbuf[0] ----
  FB wbuf[2][8];  // [buf][0..3]=wA(nt even), [4..7]=wB(nt odd)
  #pragma unroll
  for (int c = 0; c < 4; c++) {
    wbuf[0][c].i     = w1f[(0 * 4 + c) * 64];
    wbuf[0][4 + c].i = w1f[(1 * 4 + c) * 64];
  }

  #pragma unroll 1
  for (int s = 0; s < 50; s++) {
    const float dt = dtf[s];
    const float m2dt = -2.0f * dt;

    // ---- stream W2 chunk 0 (consumed at p=1; builtin MFMA) ----
    FB w2r0[8];
    #pragma unroll
    for (int tb = 0; tb < 8; tb++)
      w2r0[tb].i = w2f[tb * 64];

    // ---- states -> B-frags (pure register packing) ----
    FB hba[4], hbb[4];
    #pragma unroll
    for (int kc = 0; kc < 4; kc++) {
      hba[kc].i = packfrag(h4a[2 * kc], h4a[2 * kc + 1]);
      hbb[kc].i = packfrag(h4b[2 * kc], h4b[2 * kc + 1]);
    }

    // ---- fully-unrolled pipeline over 8 chunks ----
    // per p: prefetch W1(p+1)+bi(p+1) ; MM1(p) ; MM2(p-1) ; ACT(p)
    FB afa, afb;
    FB w2r7[8];
    float4v biN0, biN1;
    #pragma unroll
    for (int p = 0; p < 8; p++) {
      const int cur = p & 1, nxt = cur ^ 1;
      const int pn = (p < 7) ? (p + 1) : 0;  // last iter preloads next step's chunk 0
      // 1. W1 prefetch into the other buffer (consumed next iteration/step)
      #pragma unroll
      for (int c = 0; c < 4; c++) {
        wbuf[nxt][c].i     = w1f[((2 * pn) * 4 + c) * 64];
        wbuf[nxt][4 + c].i = w1f[((2 * pn + 1) * 4 + c) * 64];
      }
      // chunk-7 W2 stream in the last window (consumed by epilogue, builtin)
      if (p == 7) {
        #pragma unroll
        for (int tb = 0; tb < 8; tb++)
          w2r7[tb].i = w2f[(56 + tb) * 64];
      }
      // C-init for this chunk (prefetched last iteration; permanent for p=0)
      const float4v bc0 = (p == 0) ? bc0_0 : biN0;
      const float4v bc1 = (p == 0) ? bc0_1 : biN1;
      // 2. bi prefetch for next chunk
      if (p < 7) {
        biN0 = *(const float4v*)&b1f[(2 * p + 2) * 16 + q * 4];
        biN1 = *(const float4v*)&b1f[(2 * p + 3) * 16 + q * 4];
      }
      // 3. MM1(p) from wbuf[cur] (loaded a full iteration ago; builtin)
      float4v g0a = bc0, g1a = bc1, g0b = bc0, g1b = bc1;
      #pragma unroll
      for (int c = 0; c < 4; c++) {
        g0a = MFMA16(wbuf[cur][c].s,     hba[c].s, g0a);
        g1a = MFMA16(wbuf[cur][4 + c].s, hba[c].s, g1a);
        g0b = MFMA16(wbuf[cur][c].s,     hbb[c].s, g0b);
        g1b = MFMA16(wbuf[cur][4 + c].s, hbb[c].s, g1b);
      }
      // 4. MM2(p-1): chunk 0 via builtin (VGPR), chunks 1..6 via AGPR asm
      if (p == 1) {
        #pragma unroll
        for (int tb = 0; tb < 8; tb++) {
          h4a[tb] = MFMA16(w2r0[tb].s, afa.s, h4a[tb]);
          h4b[tb] = MFMA16(w2r0[tb].s, afb.s, h4b[tb]);
        }
      } else if (p >= 2) {
        #pragma unroll
        for (int tb = 0; tb < 8; tb++) {
          mfma_a(h4a[tb], w2c[(p - 2) * 8 + tb], afa.s);
          mfma_a(h4b[tb], w2c[(p - 2) * 8 + tb], afb.s);
        }
      }
      // 5. ACT(p): refill afa/afb (consumed by MM2 next iteration)
      float4v a0a, a1a, a0b, a1b;
      #pragma unroll
      for (int r = 0; r < 4; r++) {
        a0a[r] = fmaf(__builtin_amdgcn_rcpf(__builtin_amdgcn_exp2f(g0a[r]) + 1.0f), m2dt, dt);
        a1a[r] = fmaf(__builtin_amdgcn_rcpf(__builtin_amdgcn_exp2f(g1a[r]) + 1.0f), m2dt, dt);
        a0b[r] = fmaf(__builtin_amdgcn_rcpf(__builtin_amdgcn_exp2f(g0b[r]) + 1.0f), m2dt, dt);
        a1b[r] = fmaf(__builtin_amdgcn_rcpf(__builtin_amdgcn_exp2f(g1b[r]) + 1.0f), m2dt, dt);
      }
      afa.i = packfrag(a0a, a1a);
      afb.i = packfrag(a0b, a1b);
    }

    // epilogue: MM2(7) via builtin (compiler emits hazard nops before the
    // VALU b2-add / next-step packfrag reads of h4)
    #pragma unroll
    for (int tb = 0; tb < 8; tb++) {
      h4a[tb] = MFMA16(w2r7[tb].s, afa.s, h4a[tb]);
      h4b[tb] = MFMA16(w2r7[tb].s, afb.s, h4b[tb]);
    }

    // ---- h += dt * b2 (b2 from LDS) ----
    #pragma unroll
    for (int tb = 0; tb < 8; tb++) {
      const float4v bv = *(const float4v*)&b2f[tb * 16 + q * 4];
      #pragma unroll
      for (int r = 0; r < 4; r++) {
        h4a[tb][r] = fmaf(dt, bv[r], h4a[tb][r]);
        h4b[tb][r] = fmaf(dt, bv[r], h4b[tb][r]);
      }
    }
  }

  // ---- store both groups ----
  #pragma unroll
  for (int tb = 0; tb < 8; tb++) {
    *(float4v*)&out[rowa * 128 + tb * 16 + q * 4] = h4a[tb];
    *(float4v*)&out[rowb * 128 + tb * 16 + q * 4] = h4b[tb];
  }
}

extern "C" void kernel_launch(void* const* d_in, const int* in_sizes, int n_in,
                              void* d_out, int out_size, void* d_ws, size_t ws_size,
                              hipStream_t stream) {
  const float* inp = (const float*)d_in[0];
  const float* ts  = (const float*)d_in[1];
  const float* W1  = (const float*)d_in[2];
  const float* b1  = (const float*)d_in[3];
  const float* W2  = (const float*)d_in[4];
  const float* b2  = (const float*)d_in[5];
  hipLaunchKernelGGL(ode_kernel, dim3(256), dim3(256), 0, stream,
                     inp, ts, W1, b1, W2, b2, (float*)d_out);
}

// Round 9
// 638.832 us; speedup vs baseline: 1.2260x; 1.2260x over previous
//
#include <hip/hip_runtime.h>

// AdjointODE: h += dt * ( tanh(h@W1+b1) @ W2 + b2 ), 50 Euler steps.
// BATCH=32768, DIM=128, HID=256.
// ROUND 18: r13 TRAFFIC + r17 SCHEDULING, ZERO REGISTER GAMES.
// Ledger: r11 (2 waves/SIMD, 16 rows/wave) = LDS-issue-bound 13.3k
// cyc/step (278us). r13 (1 wave/SIMD, 32 rows/wave) halved traffic to a
// balanced 576 reads/CU/step but unroll-1 serialized every latency ->
// 18.3k cyc (382us). r12/r14/r15/r16/r17: ALL register-cache variants
// spill (>260 arch-VGPR demand = scratch; W2-in-regs family is dead).
// r18 = r13 structure + r17's schedule skeleton, weights STREAMED:
//  - full unroll over p; W1 double-buffer wbuf[2][8] (prefetch p+1
//    under p's MFMAs); bi prefetch 1 chunk ahead; chunk-0 bi hoisted;
//  - W2 chunk p-1 loaded at TOP of iter p, consumed after MM1's 16
//    MFMAs (~256cyc shadow >> 120cyc ds latency): ONE 32-reg transient;
//  - epilogue streams W2 chunk 7 (one exposed load/step, ~6us total);
//  - builtin MFMAs only (compiler owns hazards); no AGPR/asm tricks.
// Arch ledger ~260: wbuf 64, w2r 32, h4 64, hb 32, g 16, act 16, af 8,
// bi 16, misc 12; overflow = MFMA accumulators -> cheap accvgpr spill.
// Step model: LDS 7.3k cyc (wall) | MFMA 4.1k | VALU 3.2k -> ~155us ideal.
// Canary: FETCH ~9.3MB / WRITE 16MB. GB-FETCH or dur>=280 => revert r11
// (278us) and declare its LDS roofline final.

typedef __attribute__((ext_vector_type(8))) short short8;
typedef __attribute__((ext_vector_type(4))) float float4v;
typedef __attribute__((ext_vector_type(4))) int int4v;

union FB { int4v i; short8 s; };

// LDS map (bytes)
#define W1F_OFF 0        // 64 frags (nt*4+c) x 1 KB = 64 KB
#define W2F_OFF 65536    // 64 frags (p*8+tb) x 1 KB = 64 KB
#define B1_OFF  131072   // f32[256] (TSCALE-folded b1)
#define DT_OFF  132096   // f32[64]
#define B2_OFF  132352   // f32[128]
#define LDS_BYTES 132864

#define TSCALE 2.8853900817779268f  // 2/ln2: tanh(x) = 1 - 2/(exp2(x*TSCALE)+1)

__device__ __forceinline__ unsigned rne2(float x) {
  unsigned u = __float_as_uint(x);
  return u + 0x7fffu + ((u >> 16) & 1u);
}

#if __has_builtin(__builtin_amdgcn_cvt_pk_bf16_f32)
__device__ __forceinline__ int pk2(float lo, float hi) {
  return __builtin_bit_cast(int, __builtin_amdgcn_cvt_pk_bf16_f32(lo, hi));
}
#else
__device__ __forceinline__ int pk2(float lo, float hi) {
  return (int)__builtin_amdgcn_perm(rne2(hi), rne2(lo), 0x07060302u);
}
#endif

// B-frag for one 32-K chunk from two C-layout float4 tiles (even, odd).
__device__ __forceinline__ int4v packfrag(float4v e, float4v o) {
  int4v f;
  f.x = pk2(e.x, e.y);
  f.y = pk2(e.z, e.w);
  f.z = pk2(o.x, o.y);
  f.w = pk2(o.z, o.w);
  return f;
}

#define MFMA16(a, b, c) __builtin_amdgcn_mfma_f32_16x16x32_bf16(a, b, c, 0, 0, 0)

extern "C" __global__ __launch_bounds__(256, 1)
void ode_kernel(const float* __restrict__ inp, const float* __restrict__ ts,
                const float* __restrict__ W1, const float* __restrict__ b1,
                const float* __restrict__ W2, const float* __restrict__ b2,
                float* __restrict__ out) {
  __shared__ __align__(16) char ldsb[LDS_BYTES];
  float* b1f = (float*)(ldsb + B1_OFF);
  float* dtf = (float*)(ldsb + DT_OFF);
  float* b2f = (float*)(ldsb + B2_OFF);

  const int tid = threadIdx.x;
  const int lane = tid & 63, wave = tid >> 6;
  const int ln = lane & 15;  // batch-row within group
  const int q = lane >> 4;   // quad
  const int rowa = blockIdx.x * 128 + wave * 32 + ln;  // group A row
  const int rowb = rowa + 16;                          // group B row

  // ---- stage W1 frags: pi = (fid=nt*4+c)*64 + L; 256 thr x 16 iters ----
  #pragma unroll 1
  for (int it = 0; it < 16; it++) {
    const int pi = it * 256 + tid;  // [0, 4096)
    const int fid = pi >> 6, L = pi & 63;
    const int nt = fid >> 2, c = fid & 3;
    const int lf = L & 15, qf = L >> 4;
    const int n = nt * 16 + lf;            // hid index (A-frag m-row)
    const int kb = c * 32 + qf * 4;        // logical dim base
    float v0 = W1[(kb + 0) * 256 + n] * TSCALE;
    float v1 = W1[(kb + 1) * 256 + n] * TSCALE;
    float v2 = W1[(kb + 2) * 256 + n] * TSCALE;
    float v3 = W1[(kb + 3) * 256 + n] * TSCALE;
    float v4 = W1[(kb + 16) * 256 + n] * TSCALE;
    float v5 = W1[(kb + 17) * 256 + n] * TSCALE;
    float v6 = W1[(kb + 18) * 256 + n] * TSCALE;
    float v7 = W1[(kb + 19) * 256 + n] * TSCALE;
    int4v d = {pk2(v0, v1), pk2(v2, v3), pk2(v4, v5), pk2(v6, v7)};
    *(int4v*)(ldsb + W1F_OFF + pi * 16) = d;
  }
  // ---- stage W2 frags: fid = p*8 + tb ----
  #pragma unroll 1
  for (int it = 0; it < 16; it++) {
    const int pi = it * 256 + tid;
    const int fid = pi >> 6, L = pi & 63;
    const int p = fid >> 3, tb = fid & 7;
    const int lf = L & 15, qf = L >> 4;
    const int d_out = tb * 16 + lf;        // output-dim (A-frag m-row)
    const int kb = p * 32 + qf * 4;        // logical hid base
    float v0 = W2[(kb + 0) * 128 + d_out];
    float v1 = W2[(kb + 1) * 128 + d_out];
    float v2 = W2[(kb + 2) * 128 + d_out];
    float v3 = W2[(kb + 3) * 128 + d_out];
    float v4 = W2[(kb + 16) * 128 + d_out];
    float v5 = W2[(kb + 17) * 128 + d_out];
    float v6 = W2[(kb + 18) * 128 + d_out];
    float v7 = W2[(kb + 19) * 128 + d_out];
    int4v d = {pk2(v0, v1), pk2(v2, v3), pk2(v4, v5), pk2(v6, v7)};
    *(int4v*)(ldsb + W2F_OFF + pi * 16) = d;
  }
  b1f[tid] = b1[tid] * TSCALE;       // 256 threads == 256 entries
  if (tid < 128) b2f[tid] = b2[tid];
  if (tid < 50) dtf[tid] = ts[tid + 1] - ts[tid];

  // ---- load h for both groups ----
  float4v h4a[8], h4b[8];
  #pragma unroll
  for (int tb = 0; tb < 8; tb++) {
    h4a[tb] = *(const float4v*)&inp[rowa * 128 + tb * 16 + q * 4];
    h4b[tb] = *(const float4v*)&inp[rowb * 128 + tb * 16 + q * 4];
  }

  __syncthreads();  // the only barrier

  // per-lane frag base pointers
  const int4v* w1f = (const int4v*)(ldsb + W1F_OFF) + lane;
  const int4v* w2f = (const int4v*)(ldsb + W2F_OFF) + lane;

  // ---- s-invariant b1 C-init for chunk 0 (hoisted) ----
  const float4v bc0_0 = *(const float4v*)&b1f[0 * 16 + q * 4];
  const float4v bc0_1 = *(const float4v*)&b1f[1 * 16 + q * 4];

  // ---- W1 double buffer; prologue: chunk 0 -> wbuf[0] ----
  FB wbuf[2][8];  // [buf][0..3]=wA(nt even), [4..7]=wB(nt odd)
  #pragma unroll
  for (int c = 0; c < 4; c++) {
    wbuf[0][c].i     = w1f[(0 * 4 + c) * 64];
    wbuf[0][4 + c].i = w1f[(1 * 4 + c) * 64];
  }

  #pragma unroll 1
  for (int s = 0; s < 50; s++) {
    const float dt = dtf[s];
    const float m2dt = -2.0f * dt;

    // ---- states -> B-frags (pure register packing) ----
    FB hba[4], hbb[4];
    #pragma unroll
    for (int kc = 0; kc < 4; kc++) {
      hba[kc].i = packfrag(h4a[2 * kc], h4a[2 * kc + 1]);
      hbb[kc].i = packfrag(h4b[2 * kc], h4b[2 * kc + 1]);
    }

    // ---- fully-unrolled pipeline over 8 chunks ----
    // iter p: [W1 prefetch p+1] [W2 load p-1] [bi prefetch p+1]
    //         MM1(p) ; MM2(p-1) ; ACT(p)
    FB afa, afb;
    float4v biN0, biN1;
    #pragma unroll
    for (int p = 0; p < 8; p++) {
      const int cur = p & 1, nxt = cur ^ 1;
      const int pn = (p + 1) & 7;  // p=7 preloads next step's chunk 0
      // 1. W1 prefetch into the other buffer
      #pragma unroll
      for (int c = 0; c < 4; c++) {
        wbuf[nxt][c].i     = w1f[((2 * pn) * 4 + c) * 64];
        wbuf[nxt][4 + c].i = w1f[((2 * pn + 1) * 4 + c) * 64];
      }
      // 2. W2 for MM2(p-1): loaded here, consumed after MM1's 16 MFMAs
      FB w2r[8];
      if (p >= 1) {
        #pragma unroll
        for (int tb = 0; tb < 8; tb++)
          w2r[tb].i = w2f[((p - 1) * 8 + tb) * 64];
      }
      // C-init for this chunk (prefetched last iteration; hoisted for p=0)
      const float4v bc0 = (p == 0) ? bc0_0 : biN0;
      const float4v bc1 = (p == 0) ? bc0_1 : biN1;
      // 3. bi prefetch for next chunk
      if (p < 7) {
        biN0 = *(const float4v*)&b1f[(2 * p + 2) * 16 + q * 4];
        biN1 = *(const float4v*)&b1f[(2 * p + 3) * 16 + q * 4];
      }
      // 4. MM1(p) from wbuf[cur] (loaded a full iteration ago)
      float4v g0a = bc0, g1a = bc1, g0b = bc0, g1b = bc1;
      #pragma unroll
      for (int c = 0; c < 4; c++) {
        g0a = MFMA16(wbuf[cur][c].s,     hba[c].s, g0a);
        g1a = MFMA16(wbuf[cur][4 + c].s, hba[c].s, g1a);
        g0b = MFMA16(wbuf[cur][c].s,     hbb[c].s, g0b);
        g1b = MFMA16(wbuf[cur][4 + c].s, hbb[c].s, g1b);
      }
      // 5. MM2(p-1): consumes afa/afb from previous iteration
      if (p >= 1) {
        #pragma unroll
        for (int tb = 0; tb < 8; tb++) {
          h4a[tb] = MFMA16(w2r[tb].s, afa.s, h4a[tb]);
          h4b[tb] = MFMA16(w2r[tb].s, afb.s, h4b[tb]);
        }
      }
      // 6. ACT(p): refill afa/afb (consumed by MM2 next iteration)
      float4v a0a, a1a, a0b, a1b;
      #pragma unroll
      for (int r = 0; r < 4; r++) {
        a0a[r] = fmaf(__builtin_amdgcn_rcpf(__builtin_amdgcn_exp2f(g0a[r]) + 1.0f), m2dt, dt);
        a1a[r] = fmaf(__builtin_amdgcn_rcpf(__builtin_amdgcn_exp2f(g1a[r]) + 1.0f), m2dt, dt);
        a0b[r] = fmaf(__builtin_amdgcn_rcpf(__builtin_amdgcn_exp2f(g0b[r]) + 1.0f), m2dt, dt);
        a1b[r] = fmaf(__builtin_amdgcn_rcpf(__builtin_amdgcn_exp2f(g1b[r]) + 1.0f), m2dt, dt);
      }
      afa.i = packfrag(a0a, a1a);
      afb.i = packfrag(a0b, a1b);
    }

    // epilogue: stream W2 chunk 7 + MM2(7)
    {
      FB w2r7[8];
      #pragma unroll
      for (int tb = 0; tb < 8; tb++)
        w2r7[tb].i = w2f[(56 + tb) * 64];
      #pragma unroll
      for (int tb = 0; tb < 8; tb++) {
        h4a[tb] = MFMA16(w2r7[tb].s, afa.s, h4a[tb]);
        h4b[tb] = MFMA16(w2r7[tb].s, afb.s, h4b[tb]);
      }
    }

    // ---- h += dt * b2 (b2 from LDS) ----
    #pragma unroll
    for (int tb = 0; tb < 8; tb++) {
      const float4v bv = *(const float4v*)&b2f[tb * 16 + q * 4];
      #pragma unroll
      for (int r = 0; r < 4; r++) {
        h4a[tb][r] = fmaf(dt, bv[r], h4a[tb][r]);
        h4b[tb][r] = fmaf(dt, bv[r], h4b[tb][r]);
      }
    }
  }

  // ---- store both groups ----
  #pragma unroll
  for (int tb = 0; tb < 8; tb++) {
    *(float4v*)&out[rowa * 128 + tb * 16 + q * 4] = h4a[tb];
    *(float4v*)&out[rowb * 128 + tb * 16 + q * 4] = h4b[tb];
  }
}

extern "C" void kernel_launch(void* const* d_in, const int* in_sizes, int n_in,
                              void* d_out, int out_size, void* d_ws, size_t ws_size,
                              hipStream_t stream) {
  const float* inp = (const float*)d_in[0];
  const float* ts  = (const float*)d_in[1];
  const float* W1  = (const float*)d_in[2];
  const float* b1  = (const float*)d_in[3];
  const float* W2  = (const float*)d_in[4];
  const float* b2  = (const float*)d_in[5];
  hipLaunchKernelGGL(ode_kernel, dim3(256), dim3(256), 0, stream,
                     inp, ts, W1, b1, W2, b2, (float*)d_out);
}